// Round 11
// baseline (291.256 us; speedup 1.0000x reference)
//
#include <hip/hip_runtime.h>
#include <hip/hip_bf16.h>

#define N_NODES 100000
#define N_EDGES 3200000
#define N_GRAPHS 512
#define HID 64
#define OUT_DIM 10

#define NPB 64                  // nodes per dst-bucket (pow2)
#define NB  1563                // ceil(N_NODES / NPB)
#define CAP 2432                // edges/bucket capacity (mean 2047, +8.5 sigma)

// ---------------------------------------------------------------------------
// K1: partition edges into dst-range buckets. ONE LDS atomic per edge:
// rank r = atomicAdd(hist) serves as both count and in-block slot; after the
// per-bucket ranged global atomic turns hist into base, write ebuf[base+r].
__global__ __launch_bounds__(256) void k_part(const int4* __restrict__ src4,
                                              const int4* __restrict__ dst4,
                                              unsigned* __restrict__ bcur,
                                              unsigned* __restrict__ ebuf) {
    __shared__ unsigned hist[NB];   // counts, then bases
    int tid = threadIdx.x;
    for (int i = tid; i < NB; i += 256) hist[i] = 0;
    __syncthreads();
    int base4 = (blockIdx.x * 256 + tid) * 2;
    int4 s0 = make_int4(-1, -1, -1, -1), s1 = s0;
    int4 d0 = make_int4(0, 0, 0, 0), d1 = d0;
    if (base4 < N_EDGES / 4)     { s0 = src4[base4];     d0 = dst4[base4]; }
    if (base4 + 1 < N_EDGES / 4) { s1 = src4[base4 + 1]; d1 = dst4[base4 + 1]; }
    int sv[8] = { s0.x, s0.y, s0.z, s0.w, s1.x, s1.y, s1.z, s1.w };
    int dv[8] = { d0.x, d0.y, d0.z, d0.w, d1.x, d1.y, d1.z, d1.w };
    int bk[8]; unsigned rk[8];
    #pragma unroll
    for (int k = 0; k < 8; k++) {
        bk[k] = dv[k] >> 6;
        rk[k] = (sv[k] >= 0) ? atomicAdd(&hist[bk[k]], 1u) : 0u;
    }
    __syncthreads();
    for (int i = tid; i < NB; i += 256) {
        unsigned c = hist[i];
        hist[i] = c ? atomicAdd(&bcur[i], c) : 0u;    // hist becomes base
    }
    __syncthreads();
    #pragma unroll
    for (int k = 0; k < 8; k++) {
        if (sv[k] >= 0) {
            unsigned dl = (unsigned)(dv[k] & 63);
            ebuf[(size_t)bk[k] * CAP + hist[bk[k]] + rk[k]] = (dl << 24) | (unsigned)sv[k];
        }
    }
}

// ---------------------------------------------------------------------------
// K2: per-bucket degree histogram -> deg, dinv, g1, AND counting-sort
// writeback: the histogram atomic's return value is the edge's rank, so the
// same single atomic pass yields node-sorted edges in ebuf2 (dense per-bucket
// region -> fully merged cache lines on write).
__global__ __launch_bounds__(256) void k_buck1(const unsigned* __restrict__ ebuf,
                                               const unsigned* __restrict__ bcur,
                                               const float* __restrict__ x,
                                               unsigned* __restrict__ deg,
                                               float* __restrict__ dinv,
                                               float* __restrict__ g1,
                                               unsigned* __restrict__ ebuf2) {
    __shared__ unsigned cnt[NPB];
    __shared__ int offs[NPB];
    __shared__ unsigned rnk[CAP];      // 9728 B
    int b = blockIdx.x, tid = threadIdx.x;
    if (tid < NPB) cnt[tid] = 0;
    __syncthreads();
    int ec = (int)bcur[b];
    const unsigned* eb = ebuf + (size_t)b * CAP;
    unsigned* eb2 = ebuf2 + (size_t)b * CAP;
    for (int i = tid; i < ec; i += 256)
        rnk[i] = atomicAdd(&cnt[eb[i] >> 24], 1u);
    __syncthreads();
    if (tid == 0) {
        int r = 0;
        for (int i = 0; i < NPB; i++) { offs[i] = r; r += (int)cnt[i]; }
    }
    __syncthreads();
    int n0 = b * NPB;
    int nn = min(NPB, N_NODES - n0);
    if (tid < nn) {
        unsigned c = cnt[tid];
        float dn = 1.0f / sqrtf((float)c + 1.0f);   // +1: self loop
        deg[n0 + tid] = c;
        dinv[n0 + tid] = dn;
        g1[n0 + tid] = dn * x[n0 + tid];
    }
    for (int i = tid; i < ec; i += 256) {
        unsigned w = eb[i];
        eb2[offs[w >> 24] + rnk[i]] = w;
    }
}

// ---------------------------------------------------------------------------
// K3: per-bucket layer-1 scalar aggregation in LDS -> sd = (s, dinv).
__global__ __launch_bounds__(256) void k_buck2(const unsigned* __restrict__ ebuf2,
                                               const unsigned* __restrict__ bcur,
                                               const float* __restrict__ g1,
                                               const float* __restrict__ dinv,
                                               const float* __restrict__ x,
                                               float2* __restrict__ sd) {
    __shared__ float sacc[NPB];
    int b = blockIdx.x, tid = threadIdx.x;
    if (tid < NPB) sacc[tid] = 0.f;
    __syncthreads();
    int ec = (int)bcur[b];
    const unsigned* eb = ebuf2 + (size_t)b * CAP;
    for (int i = tid; i < ec; i += 256) {
        unsigned w = eb[i];
        atomicAdd(&sacc[w >> 24], g1[w & 0x00FFFFFFu]);
    }
    __syncthreads();
    int n0 = b * NPB;
    int nn = min(NPB, N_NODES - n0);
    if (tid < nn) {
        float dn = dinv[n0 + tid];
        float s = dn * (sacc[tid] + dn * x[n0 + tid]);
        sd[n0 + tid] = make_float2(s, dn);
    }
}

// ---------------------------------------------------------------------------
// K4: per-bucket layer-2 + fused pooling, SORT-FREE: edges arrive node-sorted
// in ebuf2. Wave-per-node batched gather (pipelined, n+4 prefetch) ->
// wave-private LDS stage -> b128 broadcast register accumulation.
// W2 staged in LDS (conflict-free per-j reads). Tiny LDS footprint removed ->
// occupancy at the 32-wave cap. Zero per-edge atomics.
__global__ __launch_bounds__(256) void k_buck3(const unsigned* __restrict__ ebuf2,
                                               const unsigned* __restrict__ bcur,
                                               const unsigned* __restrict__ deg,
                                               const float2* __restrict__ sd,
                                               const int* __restrict__ batch,
                                               const float* __restrict__ W1,
                                               const float* __restrict__ b1,
                                               const float* __restrict__ W2,
                                               const float* __restrict__ b2,
                                               float* __restrict__ pooled) {
    __shared__ float w2ls[HID * HID];    // 16384 B
    __shared__ float2 stage[256];        // 4 waves x 64, wave-private slices
    __shared__ int offs[NPB + 1];
    int b = blockIdx.x, tid = threadIdx.x;
    int lane = tid & 63, wv = tid >> 6;
    int n0 = b * NPB;
    int nn = min(NPB, N_NODES - n0);
    if (tid == 0) {
        int r = 0;
        for (int i = 0; i < nn; i++) { offs[i] = r; r += (int)deg[n0 + i]; }
        offs[nn] = r;
    }
    for (int i = tid; i < HID * HID; i += 256) w2ls[i] = W2[i];
    float w1 = W1[lane], bb1 = b1[lane], bb2 = b2[lane];
    __syncthreads();
    const unsigned* eb2 = ebuf2 + (size_t)b * CAP;
    float2* st = stage + wv * 64;
    const float4* stv = (const float4*)st;
    int curg = -1;
    float pacc1 = 0.f, pacc2 = 0.f;

    // prefetch helper: first <=64-edge batch of node n into registers
    auto fetchv = [&](int n) -> float2 {
        float2 v = make_float2(0.f, 0.f);
        if (n < nn) {
            int lo = offs[n];
            int m = offs[n + 1] - lo; if (m > 64) m = 64;
            if (lane < m) v = sd[eb2[lo + lane] & 0x00FFFFFFu];
        }
        return v;
    };

    float2 vcur = fetchv(wv);
    for (int n = wv; n < nn; n += 4) {
        float2 vnext = fetchv(n + 4);    // hides L2 gather under compute below
        int lo = offs[n], hi = offs[n + 1];
        int m = hi - lo; if (m > 64) m = 64;
        st[lane] = vcur;                 // wave-private; DS in-order per wave
        float acca = 0.f, accb = 0.f;
        int k = 0;
        for (; k + 1 < m; k += 2) {      // 2 edges per ds_read_b128
            float4 e = stv[k >> 1];
            acca = fmaf(e.y, fmaxf(fmaf(e.x, w1, bb1), 0.f), acca);
            accb = fmaf(e.w, fmaxf(fmaf(e.z, w1, bb1), 0.f), accb);
        }
        if (k < m) {
            float2 e0 = st[k];
            acca = fmaf(e0.y, fmaxf(fmaf(e0.x, w1, bb1), 0.f), acca);
        }
        for (int base = lo + 64; base < hi; base += 64) {   // deg>64 slow path
            int mm = hi - base; if (mm > 64) mm = 64;
            float2 v = make_float2(0.f, 0.f);
            if (lane < mm) v = sd[eb2[base + lane] & 0x00FFFFFFu];
            st[lane] = v;
            int kk = 0;
            for (; kk + 1 < mm; kk += 2) {
                float4 e = stv[kk >> 1];
                acca = fmaf(e.y, fmaxf(fmaf(e.x, w1, bb1), 0.f), acca);
                accb = fmaf(e.w, fmaxf(fmaf(e.z, w1, bb1), 0.f), accb);
            }
            if (kk < mm) {
                float2 e0 = st[kk];
                acca = fmaf(e0.y, fmaxf(fmaf(e0.x, w1, bb1), 0.f), acca);
            }
        }
        float2 self = sd[n0 + n];
        float t = fmaxf(fmaf(self.x, w1, bb1), 0.f);       // = x1[n][lane]
        float a = self.y * (acca + accb + self.y * t);     // agg[n][lane]
        float acc2a = bb2, acc2b = 0.f;
        #pragma unroll
        for (int j = 0; j < HID; j += 2) {                 // readlane matvec
            float aj0 = __int_as_float(__builtin_amdgcn_readlane(__float_as_int(a), j));
            float aj1 = __int_as_float(__builtin_amdgcn_readlane(__float_as_int(a), j + 1));
            acc2a = fmaf(aj0, w2ls[j * HID + lane], acc2a);
            acc2b = fmaf(aj1, w2ls[(j + 1) * HID + lane], acc2b);
        }
        float x2v = fmaxf(acc2a + acc2b, 0.f);             // = x2[n][lane]
        int g = batch[n0 + n];                             // uniform scalar load
        if (g != curg) {
            if (curg >= 0) {
                atomicAdd(&pooled[curg * 2 * HID + lane], pacc1);
                atomicAdd(&pooled[curg * 2 * HID + HID + lane], pacc2);
            }
            curg = g; pacc1 = 0.f; pacc2 = 0.f;
        }
        pacc1 += t;
        pacc2 += x2v;
        vcur = vnext;
    }
    if (curg >= 0) {
        atomicAdd(&pooled[curg * 2 * HID + lane], pacc1);
        atomicAdd(&pooled[curg * 2 * HID + HID + lane], pacc2);
    }
}

// ---------------------------------------------------------------------------
// K5: head: pooled/cnt -> 128x10 linear. One block (128 thr) per graph.
// Graph boundaries via binary search on sorted batch.
__global__ __launch_bounds__(128) void k_head(const float* __restrict__ pooled,
                                              const int* __restrict__ batch,
                                              const float* __restrict__ Wl,
                                              const float* __restrict__ bl,
                                              float* __restrict__ out) {
    int g = blockIdx.x;
    int t = threadIdx.x;
    int lo1 = 0, hi1 = N_NODES;
    while (lo1 < hi1) { int mid = (lo1 + hi1) >> 1; if (batch[mid] < g) lo1 = mid + 1; else hi1 = mid; }
    int lo2 = lo1, hi2 = N_NODES;
    while (lo2 < hi2) { int mid = (lo2 + hi2) >> 1; if (batch[mid] < g + 1) lo2 = mid + 1; else hi2 = mid; }
    float denom = fmaxf((float)(lo2 - lo1), 1.f);
    __shared__ float pl[2 * HID];
    pl[t] = pooled[g * 2 * HID + t] / denom;
    __syncthreads();
    if (t < OUT_DIM) {
        float r = bl[t];
        #pragma unroll 16
        for (int j = 0; j < 2 * HID; j++) r = fmaf(pl[j], Wl[j * OUT_DIM + t], r);
        out[g * OUT_DIM + t] = r;
    }
}

// ---------------------------------------------------------------------------
extern "C" void kernel_launch(void* const* d_in, const int* in_sizes, int n_in,
                              void* d_out, int out_size, void* d_ws, size_t ws_size,
                              hipStream_t stream) {
    const float* x      = (const float*)d_in[0];
    const int*   ei     = (const int*)d_in[1];           // (2, E) int32
    const int*   batch  = (const int*)d_in[2];
    const float* W1     = (const float*)d_in[3];
    const float* b1     = (const float*)d_in[4];
    const float* W2     = (const float*)d_in[5];
    const float* b2     = (const float*)d_in[6];
    const float* Wl     = (const float*)d_in[7];
    const float* bl     = (const float*)d_in[8];
    float* out = (float*)d_out;

    const int* src = ei;
    const int* dst = ei + N_EDGES;

    // workspace carve-up (256B aligned)
    char* p = (char*)d_ws;
    auto alloc = [&](size_t bytes) { void* r = (void*)p; p += (bytes + 255) & ~(size_t)255; return r; };
    unsigned* bcur   = (unsigned*)alloc(NB * 4);
    unsigned* ebuf   = (unsigned*)alloc((size_t)NB * CAP * 4);   // 15.2 MB
    unsigned* ebuf2  = (unsigned*)alloc((size_t)NB * CAP * 4);   // 15.2 MB
    unsigned* deg    = (unsigned*)alloc(N_NODES * 4);
    float*    dinv   = (float*)alloc(N_NODES * 4);
    float*    g1     = (float*)alloc(N_NODES * 4);
    float2*   sd     = (float2*)alloc((size_t)N_NODES * 8);
    float*    pooled = (float*)alloc((size_t)N_GRAPHS * 2 * HID * 4);

    hipMemsetAsync(bcur, 0, NB * 4, stream);
    hipMemsetAsync(pooled, 0, (size_t)N_GRAPHS * 2 * HID * 4, stream);

    const int TB = 256;
    int pbl = (N_EDGES / 8 + TB - 1) / TB;    // 8 edges per thread

    k_part <<<pbl, TB, 0, stream>>>((const int4*)src, (const int4*)dst, bcur, ebuf);
    k_buck1<<<NB, TB, 0, stream>>>(ebuf, bcur, x, deg, dinv, g1, ebuf2);
    k_buck2<<<NB, TB, 0, stream>>>(ebuf2, bcur, g1, dinv, x, sd);
    k_buck3<<<NB, TB, 0, stream>>>(ebuf2, bcur, deg, sd, batch, W1, b1, W2, b2, pooled);
    k_head <<<N_GRAPHS, 128, 0, stream>>>(pooled, batch, Wl, bl, out);
}

// Round 13
// 266.854 us; speedup vs baseline: 1.0914x; 1.0914x over previous
//
#include <hip/hip_runtime.h>
#include <hip/hip_bf16.h>

#define N_NODES 100000
#define N_EDGES 3200000
#define N_GRAPHS 512
#define HID 64
#define OUT_DIM 10

#define NPB 64                  // nodes per dst-bucket (pow2)
#define NB  1563                // ceil(N_NODES / NPB)
#define CAP 2432                // edges/bucket capacity (mean 2047, +8.5 sigma)
#define CAP2 (CAP + NPB)        // stage capacity with per-node even-padding

// Packed edge word: src[16:0] | dl[22:17] | rank[31:23]
// (src < 2^17, dl < 64, rank < 512 — deg>511 has ~0 probability at Poisson(32))

// ---------------------------------------------------------------------------
// K1: partition edges into dst-range buckets. ONE LDS atomic per edge:
// rank r = atomicAdd(hist) is both count and in-block slot; after the ranged
// global atomic turns hist into base, write ebuf[base+r].
__global__ __launch_bounds__(256) void k_part(const int4* __restrict__ src4,
                                              const int4* __restrict__ dst4,
                                              unsigned* __restrict__ bcur,
                                              unsigned* __restrict__ ebuf) {
    __shared__ unsigned hist[NB];   // counts, then bases
    int tid = threadIdx.x;
    for (int i = tid; i < NB; i += 256) hist[i] = 0;
    __syncthreads();
    int base4 = (blockIdx.x * 256 + tid) * 2;
    int4 s0 = make_int4(-1, -1, -1, -1), s1 = s0;
    int4 d0 = make_int4(0, 0, 0, 0), d1 = d0;
    if (base4 < N_EDGES / 4)     { s0 = src4[base4];     d0 = dst4[base4]; }
    if (base4 + 1 < N_EDGES / 4) { s1 = src4[base4 + 1]; d1 = dst4[base4 + 1]; }
    int sv[8] = { s0.x, s0.y, s0.z, s0.w, s1.x, s1.y, s1.z, s1.w };
    int dv[8] = { d0.x, d0.y, d0.z, d0.w, d1.x, d1.y, d1.z, d1.w };
    int bk[8]; unsigned rk[8];
    #pragma unroll
    for (int k = 0; k < 8; k++) {
        bk[k] = dv[k] >> 6;
        rk[k] = (sv[k] >= 0) ? atomicAdd(&hist[bk[k]], 1u) : 0u;
    }
    __syncthreads();
    for (int i = tid; i < NB; i += 256) {
        unsigned c = hist[i];
        hist[i] = c ? atomicAdd(&bcur[i], c) : 0u;    // hist becomes base
    }
    __syncthreads();
    #pragma unroll
    for (int k = 0; k < 8; k++) {
        if (sv[k] >= 0) {
            unsigned dl = (unsigned)(dv[k] & 63);
            ebuf[(size_t)bk[k] * CAP + hist[bk[k]] + rk[k]] = (dl << 17) | (unsigned)sv[k];
        }
    }
}

// ---------------------------------------------------------------------------
// K2: per-bucket degree histogram -> deg, dinv, g1; the histogram atomic's
// return value is the edge's within-node rank -> embed it in the word and
// write back IN PLACE (coalesced read-modify-write, no extra buffer).
__global__ __launch_bounds__(256) void k_buck1(unsigned* __restrict__ ebuf,
                                               const unsigned* __restrict__ bcur,
                                               const float* __restrict__ x,
                                               unsigned* __restrict__ deg,
                                               float* __restrict__ dinv,
                                               float* __restrict__ g1) {
    __shared__ unsigned cnt[NPB];
    int b = blockIdx.x, tid = threadIdx.x;
    if (tid < NPB) cnt[tid] = 0;
    __syncthreads();
    int ec = (int)bcur[b];
    unsigned* eb = ebuf + (size_t)b * CAP;
    for (int i = tid; i < ec; i += 256) {
        unsigned w = eb[i];
        unsigned rk = atomicAdd(&cnt[(w >> 17) & 63], 1u);
        eb[i] = w | (rk << 23);
    }
    __syncthreads();
    int n0 = b * NPB;
    int nn = min(NPB, N_NODES - n0);
    if (tid < nn) {
        unsigned c = cnt[tid];
        float dn = 1.0f / sqrtf((float)c + 1.0f);   // +1: self loop
        deg[n0 + tid] = c;
        dinv[n0 + tid] = dn;
        g1[n0 + tid] = dn * x[n0 + tid];
    }
}

// ---------------------------------------------------------------------------
// K3: per-bucket layer-1 scalar aggregation in LDS -> sd = (s, dinv).
__global__ __launch_bounds__(256) void k_buck2(const unsigned* __restrict__ ebuf,
                                               const unsigned* __restrict__ bcur,
                                               const float* __restrict__ g1,
                                               const float* __restrict__ dinv,
                                               const float* __restrict__ x,
                                               float2* __restrict__ sd) {
    __shared__ float sacc[NPB];
    int b = blockIdx.x, tid = threadIdx.x;
    if (tid < NPB) sacc[tid] = 0.f;
    __syncthreads();
    int ec = (int)bcur[b];
    const unsigned* eb = ebuf + (size_t)b * CAP;
    for (int i = tid; i < ec; i += 256) {
        unsigned w = eb[i];
        atomicAdd(&sacc[(w >> 17) & 63], g1[w & 0x1FFFFu]);
    }
    __syncthreads();
    int n0 = b * NPB;
    int nn = min(NPB, N_NODES - n0);
    if (tid < nn) {
        float dn = dinv[n0 + tid];
        float s = dn * (sacc[tid] + dn * x[n0 + tid]);
        sd[n0 + tid] = make_float2(s, dn);
    }
}

// ---------------------------------------------------------------------------
// K4: per-bucket layer-2 + fused pooling. ATOMIC-FREE:
// phase 1: block-cooperative fused sort+gather — all 256 threads stream the
//   bucket's edges (dense lanes, deep MLP), writing sd[src] straight into
//   stage2[offs[dl]+rank] (LDS scatter is cheap; ranks precomputed in buck1).
// phase 2: wave-per-node pure broadcast ds_read_b128 + register accumulation;
//   node regions even-padded so b128 pairs stay 16B-aligned. W2 in LDS.
__global__ __launch_bounds__(256) void k_buck3(const unsigned* __restrict__ ebuf,
                                               const unsigned* __restrict__ bcur,
                                               const unsigned* __restrict__ deg,
                                               const float2* __restrict__ sd,
                                               const int* __restrict__ batch,
                                               const float* __restrict__ W1,
                                               const float* __restrict__ b1,
                                               const float* __restrict__ W2,
                                               const float* __restrict__ b2,
                                               float* __restrict__ pooled) {
    __shared__ __align__(16) float2 stage2[CAP2];   // 19968 B
    __shared__ float w2ls[HID * HID];               // 16384 B
    __shared__ int offs[NPB + 1];
    __shared__ int degs[NPB];
    int b = blockIdx.x, tid = threadIdx.x;
    int lane = tid & 63, wv = tid >> 6;
    int n0 = b * NPB;
    int nn = min(NPB, N_NODES - n0);
    for (int i = tid; i < HID * HID; i += 256) w2ls[i] = W2[i];
    if (wv == 0) {                     // wave-parallel padded prefix scan
        int d = (lane < nn) ? (int)deg[n0 + lane] : 0;
        degs[lane] = d;
        int dp = (d + 1) & ~1;         // even-pad each node's region
        int sum = dp;
        #pragma unroll
        for (int o = 1; o < 64; o <<= 1) {
            int t = __shfl_up(sum, o, 64);
            if (lane >= o) sum += t;
        }
        offs[lane + 1] = sum;          // inclusive ends (lane 63 sets offs[64])
        offs[lane]     = sum - dp;     // exclusive starts (identical overwrite)
        if (lane == 0) offs[0] = 0;
    }
    float w1 = W1[lane], bb1 = b1[lane], bb2 = b2[lane];
    __syncthreads();
    // phase 1: fused sort+gather into stage2 (no atomics)
    int ec = (int)bcur[b];
    const unsigned* eb = ebuf + (size_t)b * CAP;
    for (int i = tid; i < ec; i += 256) {
        unsigned w = eb[i];
        stage2[offs[(w >> 17) & 63] + (w >> 23)] = sd[w & 0x1FFFFu];
    }
    __syncthreads();
    // phase 2: wave-per-node broadcast accumulation + matvec + pooling
    const float4* stv = (const float4*)stage2;
    int curg = -1;
    float pacc1 = 0.f, pacc2 = 0.f;
    for (int n = wv; n < nn; n += 4) {
        int lo = offs[n];              // even
        int m = degs[n];
        float acca = 0.f, accb = 0.f;
        int half = m >> 1;
        int p0 = lo >> 1;
        for (int k = 0; k < half; k++) {           // 2 edges per ds_read_b128
            float4 e = stv[p0 + k];
            acca = fmaf(e.y, fmaxf(fmaf(e.x, w1, bb1), 0.f), acca);
            accb = fmaf(e.w, fmaxf(fmaf(e.z, w1, bb1), 0.f), accb);
        }
        if (m & 1) {
            float2 e0 = stage2[lo + m - 1];
            acca = fmaf(e0.y, fmaxf(fmaf(e0.x, w1, bb1), 0.f), acca);
        }
        float2 self = sd[n0 + n];
        float t = fmaxf(fmaf(self.x, w1, bb1), 0.f);       // = x1[n][lane]
        float a = self.y * (acca + accb + self.y * t);     // agg[n][lane]
        float acc2a = bb2, acc2b = 0.f;
        #pragma unroll
        for (int j = 0; j < HID; j += 2) {                 // readlane matvec
            float aj0 = __int_as_float(__builtin_amdgcn_readlane(__float_as_int(a), j));
            float aj1 = __int_as_float(__builtin_amdgcn_readlane(__float_as_int(a), j + 1));
            acc2a = fmaf(aj0, w2ls[j * HID + lane], acc2a);
            acc2b = fmaf(aj1, w2ls[(j + 1) * HID + lane], acc2b);
        }
        float x2v = fmaxf(acc2a + acc2b, 0.f);             // = x2[n][lane]
        int g = batch[n0 + n];                             // uniform scalar load
        if (g != curg) {
            if (curg >= 0) {
                atomicAdd(&pooled[curg * 2 * HID + lane], pacc1);
                atomicAdd(&pooled[curg * 2 * HID + HID + lane], pacc2);
            }
            curg = g; pacc1 = 0.f; pacc2 = 0.f;
        }
        pacc1 += t;
        pacc2 += x2v;
    }
    if (curg >= 0) {
        atomicAdd(&pooled[curg * 2 * HID + lane], pacc1);
        atomicAdd(&pooled[curg * 2 * HID + HID + lane], pacc2);
    }
}

// ---------------------------------------------------------------------------
// K5: head: pooled/cnt -> 128x10 linear. One block (128 thr) per graph.
// Graph boundaries via binary search on sorted batch.
__global__ __launch_bounds__(128) void k_head(const float* __restrict__ pooled,
                                              const int* __restrict__ batch,
                                              const float* __restrict__ Wl,
                                              const float* __restrict__ bl,
                                              float* __restrict__ out) {
    int g = blockIdx.x;
    int t = threadIdx.x;
    int lo1 = 0, hi1 = N_NODES;
    while (lo1 < hi1) { int mid = (lo1 + hi1) >> 1; if (batch[mid] < g) lo1 = mid + 1; else hi1 = mid; }
    int lo2 = lo1, hi2 = N_NODES;
    while (lo2 < hi2) { int mid = (lo2 + hi2) >> 1; if (batch[mid] < g + 1) lo2 = mid + 1; else hi2 = mid; }
    float denom = fmaxf((float)(lo2 - lo1), 1.f);
    __shared__ float pl[2 * HID];
    pl[t] = pooled[g * 2 * HID + t] / denom;
    __syncthreads();
    if (t < OUT_DIM) {
        float r = bl[t];
        #pragma unroll 16
        for (int j = 0; j < 2 * HID; j++) r = fmaf(pl[j], Wl[j * OUT_DIM + t], r);
        out[g * OUT_DIM + t] = r;
    }
}

// ---------------------------------------------------------------------------
extern "C" void kernel_launch(void* const* d_in, const int* in_sizes, int n_in,
                              void* d_out, int out_size, void* d_ws, size_t ws_size,
                              hipStream_t stream) {
    const float* x      = (const float*)d_in[0];
    const int*   ei     = (const int*)d_in[1];           // (2, E) int32
    const int*   batch  = (const int*)d_in[2];
    const float* W1     = (const float*)d_in[3];
    const float* b1     = (const float*)d_in[4];
    const float* W2     = (const float*)d_in[5];
    const float* b2     = (const float*)d_in[6];
    const float* Wl     = (const float*)d_in[7];
    const float* bl     = (const float*)d_in[8];
    float* out = (float*)d_out;

    const int* src = ei;
    const int* dst = ei + N_EDGES;

    // workspace carve-up (256B aligned)
    char* p = (char*)d_ws;
    auto alloc = [&](size_t bytes) { void* r = (void*)p; p += (bytes + 255) & ~(size_t)255; return r; };
    unsigned* bcur   = (unsigned*)alloc(NB * 4);
    unsigned* ebuf   = (unsigned*)alloc((size_t)NB * CAP * 4);   // 15.2 MB
    unsigned* deg    = (unsigned*)alloc(N_NODES * 4);
    float*    dinv   = (float*)alloc(N_NODES * 4);
    float*    g1     = (float*)alloc(N_NODES * 4);
    float2*   sd     = (float2*)alloc((size_t)N_NODES * 8);
    float*    pooled = (float*)alloc((size_t)N_GRAPHS * 2 * HID * 4);

    hipMemsetAsync(bcur, 0, NB * 4, stream);
    hipMemsetAsync(pooled, 0, (size_t)N_GRAPHS * 2 * HID * 4, stream);

    const int TB = 256;
    int pbl = (N_EDGES / 8 + TB - 1) / TB;    // 8 edges per thread

    k_part <<<pbl, TB, 0, stream>>>((const int4*)src, (const int4*)dst, bcur, ebuf);
    k_buck1<<<NB, TB, 0, stream>>>(ebuf, bcur, x, deg, dinv, g1);
    k_buck2<<<NB, TB, 0, stream>>>(ebuf, bcur, g1, dinv, x, sd);
    k_buck3<<<NB, TB, 0, stream>>>(ebuf, bcur, deg, sd, batch, W1, b1, W2, b2, pooled);
    k_head <<<N_GRAPHS, 128, 0, stream>>>(pooled, batch, Wl, bl, out);
}

// Round 14
// 251.501 us; speedup vs baseline: 1.1581x; 1.0610x over previous
//
#include <hip/hip_runtime.h>
#include <hip/hip_bf16.h>

#define N_NODES 100000
#define N_EDGES 3200000
#define N_GRAPHS 512
#define HID 64
#define OUT_DIM 10

#define NPC 256                 // nodes per coarse bucket (dst>>8)
#define NCB 391                 // ceil(N_NODES / NPC)
#define CAPA 8960               // edges/coarse capacity (mean 8184, +8.6 sigma)
#define NPB 64                  // nodes per fine bucket
#define NFB 1563                // ceil(N_NODES / NPB)
#define CAPF 2432               // max edges per fine bucket (mean 2047, +8.5 sigma)
#define CAP2 (CAPF + NPB)       // buck3 stage capacity with per-node even-padding

// ebufA word: (dlocal8 << 17) | src17      (dlocal within coarse bucket)
// ebufB word: (dlocal6 << 17) | src17      (dlocal within fine bucket), node-sorted

// ---------------------------------------------------------------------------
// K1: coarse partition by dst>>8. 4096 edges/block; ranks staged in LDS u16.
// One LDS-atomic pass; ~300K block-aggregated global atomics; runs ~10 words.
__global__ __launch_bounds__(256) void k_partA(const int4* __restrict__ src4,
                                               const int4* __restrict__ dst4,
                                               unsigned* __restrict__ bcurA,
                                               unsigned* __restrict__ ebufA) {
    __shared__ unsigned hist[NCB];          // counts, then bases
    __shared__ unsigned short rk16[4096];
    int tid = threadIdx.x;
    for (int i = tid; i < NCB; i += 256) hist[i] = 0;
    __syncthreads();
    int blk4 = blockIdx.x * 1024;
    #pragma unroll
    for (int k = 0; k < 4; k++) {           // pass 1: dst only -> count+rank
        int i4 = blk4 + k * 256 + tid;
        if (i4 < N_EDGES / 4) {
            int4 d = dst4[i4];
            int li = (k * 256 + tid) * 4;
            rk16[li + 0] = (unsigned short)atomicAdd(&hist[d.x >> 8], 1u);
            rk16[li + 1] = (unsigned short)atomicAdd(&hist[d.y >> 8], 1u);
            rk16[li + 2] = (unsigned short)atomicAdd(&hist[d.z >> 8], 1u);
            rk16[li + 3] = (unsigned short)atomicAdd(&hist[d.w >> 8], 1u);
        }
    }
    __syncthreads();
    for (int i = tid; i < NCB; i += 256) {
        unsigned c = hist[i];
        hist[i] = c ? atomicAdd(&bcurA[i], c) : 0u;     // hist becomes base
    }
    __syncthreads();
    #pragma unroll
    for (int k = 0; k < 4; k++) {           // pass 2: re-read, write
        int i4 = blk4 + k * 256 + tid;
        if (i4 < N_EDGES / 4) {
            int4 s = src4[i4];
            int4 d = dst4[i4];
            int li = (k * 256 + tid) * 4;
            int ss[4] = { s.x, s.y, s.z, s.w };
            int dd[4] = { d.x, d.y, d.z, d.w };
            #pragma unroll
            for (int m = 0; m < 4; m++) {
                int b = dd[m] >> 8;
                unsigned dl = (unsigned)(dd[m] & 255);
                ebufA[(size_t)b * CAPA + hist[b] + rk16[li + m]] = (dl << 17) | (unsigned)ss[m];
            }
        }
    }
}

// ---------------------------------------------------------------------------
// K2: one block per coarse bucket. Per-node histogram (atomic ret = rank) ->
// deg/dinv/g1 (absorbs old buck1); permute edges node-sorted in LDS; burst
// coalesced write to ebufB; emit fineStart/fineCnt for 4 fine sub-buckets.
__global__ __launch_bounds__(256) void k_partB(const unsigned* __restrict__ ebufA,
                                               const unsigned* __restrict__ bcurA,
                                               const float* __restrict__ x,
                                               unsigned* __restrict__ deg,
                                               float* __restrict__ dinv,
                                               float* __restrict__ g1,
                                               unsigned* __restrict__ ebufB,
                                               int* __restrict__ fineStart,
                                               int* __restrict__ fineCnt) {
    __shared__ unsigned cnt[NPC];
    __shared__ int offs[NPC + 1];
    __shared__ unsigned short rk16[CAPA];    // 17920 B
    __shared__ unsigned sorted[CAPA];        // 35840 B
    int cb = blockIdx.x, tid = threadIdx.x;
    int n0 = cb * NPC;
    int nn = min(NPC, N_NODES - n0);
    if (tid < NPC) cnt[tid] = 0;
    __syncthreads();
    int ec = (int)bcurA[cb];
    const unsigned* eb = ebufA + (size_t)cb * CAPA;
    for (int i = tid; i < ec; i += 256)
        rk16[i] = (unsigned short)atomicAdd(&cnt[eb[i] >> 17], 1u);
    __syncthreads();
    if (tid == 0) {                          // serial 256-scan, ~2K cy
        int r = 0;
        for (int i = 0; i < NPC; i++) { offs[i] = r; r += (int)cnt[i]; }
        offs[NPC] = r;
    }
    __syncthreads();
    if (tid < nn) {
        unsigned c = cnt[tid];
        float dn = 1.0f / sqrtf((float)c + 1.0f);       // +1: self loop
        deg[n0 + tid] = c;
        dinv[n0 + tid] = dn;
        g1[n0 + tid] = dn * x[n0 + tid];
    }
    if (tid < 4) {                           // fine sub-bucket metadata
        int fb = cb * 4 + tid;
        if (fb < NFB) {
            int a = tid * 64;
            int bnd = min(a + 64, nn);
            int st = (a < nn) ? offs[a] : offs[nn];
            int en = (a < nn) ? offs[bnd] : offs[nn];
            fineStart[fb] = (int)((size_t)cb * CAPA) + st;
            fineCnt[fb] = en - st;
        }
    }
    // permute node-sorted into LDS, then burst out coalesced
    for (int i = tid; i < ec; i += 256) {
        unsigned w = eb[i];
        unsigned dl8 = w >> 17;
        sorted[offs[dl8] + rk16[i]] = ((dl8 & 63u) << 17) | (w & 0x1FFFFu);
    }
    __syncthreads();
    unsigned* ob = ebufB + (size_t)cb * CAPA;
    for (int i = tid; i < ec; i += 256) ob[i] = sorted[i];
}

// ---------------------------------------------------------------------------
// K3: per-fine-bucket layer-1 scalar aggregation in LDS -> sd = (s, dinv).
__global__ __launch_bounds__(256) void k_buck2(const unsigned* __restrict__ ebufB,
                                               const int* __restrict__ fineStart,
                                               const int* __restrict__ fineCnt,
                                               const float* __restrict__ g1,
                                               const float* __restrict__ dinv,
                                               const float* __restrict__ x,
                                               float2* __restrict__ sd) {
    __shared__ float sacc[NPB];
    int fb = blockIdx.x, tid = threadIdx.x;
    if (tid < NPB) sacc[tid] = 0.f;
    __syncthreads();
    int st = fineStart[fb], ec = fineCnt[fb];
    for (int i = tid; i < ec; i += 256) {
        unsigned w = ebufB[st + i];
        atomicAdd(&sacc[(w >> 17) & 63u], g1[w & 0x1FFFFu]);
    }
    __syncthreads();
    int n0 = fb * NPB;
    int nn = min(NPB, N_NODES - n0);
    if (tid < nn) {
        float dn = dinv[n0 + tid];
        float s = dn * (sacc[tid] + dn * x[n0 + tid]);
        sd[n0 + tid] = make_float2(s, dn);
    }
}

// ---------------------------------------------------------------------------
// K4: per-fine-bucket layer-2 + fused pooling, SORT-FREE (edges node-sorted):
// phase 1: dense streaming gather sd[src] -> padded LDS layout,
// phase 2: wave-per-node broadcast ds_read_b128 + register accumulation,
//          readlane W2 matvec (W2 in LDS), per-graph register pooling.
__global__ __launch_bounds__(256) void k_buck3(const unsigned* __restrict__ ebufB,
                                               const int* __restrict__ fineStart,
                                               const int* __restrict__ fineCnt,
                                               const unsigned* __restrict__ deg,
                                               const float2* __restrict__ sd,
                                               const int* __restrict__ batch,
                                               const float* __restrict__ W1,
                                               const float* __restrict__ b1,
                                               const float* __restrict__ W2,
                                               const float* __restrict__ b2,
                                               float* __restrict__ pooled) {
    __shared__ __align__(16) float2 stage2[CAP2];   // 19968 B
    __shared__ float w2ls[HID * HID];               // 16384 B
    __shared__ int poffs[NPB + 1];                  // padded starts (even)
    __shared__ int nstart[NPB];                     // unpadded slice-local starts
    __shared__ int degs[NPB];
    int fb = blockIdx.x, tid = threadIdx.x;
    int lane = tid & 63, wv = tid >> 6;
    int n0 = fb * NPB;
    int nn = min(NPB, N_NODES - n0);
    for (int i = tid; i < HID * HID; i += 256) w2ls[i] = W2[i];
    if (wv == 0) {                     // dual wave-parallel prefix scans
        int d = (lane < nn) ? (int)deg[n0 + lane] : 0;
        degs[lane] = d;
        int dp = (d + 1) & ~1;         // even-pad each node's region
        int s1 = dp, s2 = d;
        #pragma unroll
        for (int o = 1; o < 64; o <<= 1) {
            int t1 = __shfl_up(s1, o, 64);
            int t2 = __shfl_up(s2, o, 64);
            if (lane >= o) { s1 += t1; s2 += t2; }
        }
        poffs[lane + 1] = s1;          // inclusive padded end
        poffs[lane]     = s1 - dp;     // exclusive padded start (identical overwrite)
        if (lane == 0) poffs[0] = 0;
        nstart[lane] = s2 - d;         // exclusive unpadded start
    }
    float w1 = W1[lane], bb1 = b1[lane], bb2 = b2[lane];
    __syncthreads();
    // phase 1: dense gather into padded layout (no sort, no atomics)
    int st = fineStart[fb], ec = fineCnt[fb];
    for (int i = tid; i < ec; i += 256) {
        unsigned w = ebufB[st + i];
        int dl = (int)((w >> 17) & 63u);
        stage2[poffs[dl] + (i - nstart[dl])] = sd[w & 0x1FFFFu];
    }
    __syncthreads();
    // phase 2: wave-per-node broadcast accumulation + matvec + pooling
    const float4* stv = (const float4*)stage2;
    int curg = -1;
    float pacc1 = 0.f, pacc2 = 0.f;
    for (int n = wv; n < nn; n += 4) {
        int lo = poffs[n];             // even
        int m = degs[n];
        float acca = 0.f, accb = 0.f;
        int half = m >> 1;
        int p0 = lo >> 1;
        for (int k = 0; k < half; k++) {           // 2 edges per ds_read_b128
            float4 e = stv[p0 + k];
            acca = fmaf(e.y, fmaxf(fmaf(e.x, w1, bb1), 0.f), acca);
            accb = fmaf(e.w, fmaxf(fmaf(e.z, w1, bb1), 0.f), accb);
        }
        if (m & 1) {
            float2 e0 = stage2[lo + m - 1];
            acca = fmaf(e0.y, fmaxf(fmaf(e0.x, w1, bb1), 0.f), acca);
        }
        float2 self = sd[n0 + n];
        float t = fmaxf(fmaf(self.x, w1, bb1), 0.f);       // = x1[n][lane]
        float a = self.y * (acca + accb + self.y * t);     // agg[n][lane]
        float acc2a = bb2, acc2b = 0.f;
        #pragma unroll
        for (int j = 0; j < HID; j += 2) {                 // readlane matvec
            float aj0 = __int_as_float(__builtin_amdgcn_readlane(__float_as_int(a), j));
            float aj1 = __int_as_float(__builtin_amdgcn_readlane(__float_as_int(a), j + 1));
            acc2a = fmaf(aj0, w2ls[j * HID + lane], acc2a);
            acc2b = fmaf(aj1, w2ls[(j + 1) * HID + lane], acc2b);
        }
        float x2v = fmaxf(acc2a + acc2b, 0.f);             // = x2[n][lane]
        int g = batch[n0 + n];                             // uniform scalar load
        if (g != curg) {
            if (curg >= 0) {
                atomicAdd(&pooled[curg * 2 * HID + lane], pacc1);
                atomicAdd(&pooled[curg * 2 * HID + HID + lane], pacc2);
            }
            curg = g; pacc1 = 0.f; pacc2 = 0.f;
        }
        pacc1 += t;
        pacc2 += x2v;
    }
    if (curg >= 0) {
        atomicAdd(&pooled[curg * 2 * HID + lane], pacc1);
        atomicAdd(&pooled[curg * 2 * HID + HID + lane], pacc2);
    }
}

// ---------------------------------------------------------------------------
// K5: head: pooled/cnt -> 128x10 linear. One block (128 thr) per graph.
// Graph boundaries via binary search on sorted batch.
__global__ __launch_bounds__(128) void k_head(const float* __restrict__ pooled,
                                              const int* __restrict__ batch,
                                              const float* __restrict__ Wl,
                                              const float* __restrict__ bl,
                                              float* __restrict__ out) {
    int g = blockIdx.x;
    int t = threadIdx.x;
    int lo1 = 0, hi1 = N_NODES;
    while (lo1 < hi1) { int mid = (lo1 + hi1) >> 1; if (batch[mid] < g) lo1 = mid + 1; else hi1 = mid; }
    int lo2 = lo1, hi2 = N_NODES;
    while (lo2 < hi2) { int mid = (lo2 + hi2) >> 1; if (batch[mid] < g + 1) lo2 = mid + 1; else hi2 = mid; }
    float denom = fmaxf((float)(lo2 - lo1), 1.f);
    __shared__ float pl[2 * HID];
    pl[t] = pooled[g * 2 * HID + t] / denom;
    __syncthreads();
    if (t < OUT_DIM) {
        float r = bl[t];
        #pragma unroll 16
        for (int j = 0; j < 2 * HID; j++) r = fmaf(pl[j], Wl[j * OUT_DIM + t], r);
        out[g * OUT_DIM + t] = r;
    }
}

// ---------------------------------------------------------------------------
extern "C" void kernel_launch(void* const* d_in, const int* in_sizes, int n_in,
                              void* d_out, int out_size, void* d_ws, size_t ws_size,
                              hipStream_t stream) {
    const float* x      = (const float*)d_in[0];
    const int*   ei     = (const int*)d_in[1];           // (2, E) int32
    const int*   batch  = (const int*)d_in[2];
    const float* W1     = (const float*)d_in[3];
    const float* b1     = (const float*)d_in[4];
    const float* W2     = (const float*)d_in[5];
    const float* b2     = (const float*)d_in[6];
    const float* Wl     = (const float*)d_in[7];
    const float* bl     = (const float*)d_in[8];
    float* out = (float*)d_out;

    const int* src = ei;
    const int* dst = ei + N_EDGES;

    // workspace carve-up (256B aligned)
    char* p = (char*)d_ws;
    auto alloc = [&](size_t bytes) { void* r = (void*)p; p += (bytes + 255) & ~(size_t)255; return r; };
    unsigned* bcurA    = (unsigned*)alloc(NCB * 4);
    unsigned* ebufA    = (unsigned*)alloc((size_t)NCB * CAPA * 4);   // 14.0 MB
    unsigned* ebufB    = (unsigned*)alloc((size_t)NCB * CAPA * 4);   // 14.0 MB
    unsigned* deg      = (unsigned*)alloc(N_NODES * 4);
    float*    dinv     = (float*)alloc(N_NODES * 4);
    float*    g1       = (float*)alloc(N_NODES * 4);
    float2*   sd       = (float2*)alloc((size_t)N_NODES * 8);
    int*      fineStart= (int*)alloc(NFB * 4);
    int*      fineCnt  = (int*)alloc(NFB * 4);
    float*    pooled   = (float*)alloc((size_t)N_GRAPHS * 2 * HID * 4);

    hipMemsetAsync(bcurA, 0, NCB * 4, stream);
    hipMemsetAsync(pooled, 0, (size_t)N_GRAPHS * 2 * HID * 4, stream);

    const int TB = 256;
    int abl = (N_EDGES / 4 + 1023) / 1024;    // 782 blocks, 4096 edges each

    k_partA<<<abl, TB, 0, stream>>>((const int4*)src, (const int4*)dst, bcurA, ebufA);
    k_partB<<<NCB, TB, 0, stream>>>(ebufA, bcurA, x, deg, dinv, g1, ebufB, fineStart, fineCnt);
    k_buck2<<<NFB, TB, 0, stream>>>(ebufB, fineStart, fineCnt, g1, dinv, x, sd);
    k_buck3<<<NFB, TB, 0, stream>>>(ebufB, fineStart, fineCnt, deg, sd, batch, W1, b1, W2, b2, pooled);
    k_head <<<N_GRAPHS, 128, 0, stream>>>(pooled, batch, Wl, bl, out);
}